// Round 6
// baseline (8895.941 us; speedup 1.0000x reference)
//
#include <hip/hip_runtime.h>
#include <hip/hip_bf16.h>
#include <cstdint>
#include <cstddef>

// ---------------- model dims ----------------
#define B_SZ    2048
#define H_SZ    512
#define G4      2048      // 4*H
#define TSTEPS  21
#define MAXLEN  1000
#define KIH     1024      // padded input-K (layer0: 1000->1024 ; layer1: 2H=1024)
#define KCAT    1536      // KIH + H_SZ
#define NCLS    10

// ---------------- GEMM tile ----------------
#define BM 128
#define BN 64
#define BK 32
#define LDSK 40           // padded LDS K-stride (elements); 80 B keeps 16B alignment
#define GPAD 33           // gates chunk stride (floats)

typedef short bf16x8 __attribute__((ext_vector_type(8)));            // 8 bf16 (4 VGPRs)
typedef float f32x4  __attribute__((ext_vector_type(4)));
typedef unsigned short ushort8 __attribute__((ext_vector_type(8)));  // 16B vector

__device__ __forceinline__ unsigned short f2bf(float f) {
  __hip_bfloat16 h = __float2bfloat16(f);
  unsigned short u;
  __builtin_memcpy(&u, &h, sizeof(u));
  return u;
}
__device__ __forceinline__ float bf2f(unsigned short u) {
  __hip_bfloat16 h;
  __builtin_memcpy(&h, &u, sizeof(h));
  return __bfloat162float(h);
}

__device__ __forceinline__ float sigmoidf_(float x) {
  x = fminf(fmaxf(x, -30.f), 30.f);
  return 1.f / (1.f + __expf(-x));
}
__device__ __forceinline__ float tanhf_(float x) {
  float xc = fminf(fmaxf(x, -15.f), 15.f);
  float e = __expf(2.f * xc);
  return (e - 1.f) / (e + 1.f);
}

// ============================================================
// prep: pack B[d][p][c] = [W_ih (padded to KIH) | W_hh], rows permuted,
// SPLIT into bf16 hi + lo (w ≈ hi + lo, ~16 mantissa bits).
// p = 4*j + type  <->  orig gate row r = type*512 + j   (i,f,g,o order)
// ============================================================
__global__ void prep_w_kernel(const float* __restrict__ w_ih0,
                              const float* __restrict__ w_hh0,
                              const float* __restrict__ w_ih1,
                              const float* __restrict__ w_hh1,
                              unsigned short* __restrict__ Bhi0,
                              unsigned short* __restrict__ Blo0,
                              unsigned short* __restrict__ Bhi1,
                              unsigned short* __restrict__ Blo1) {
  size_t idx = (size_t)blockIdx.x * blockDim.x + threadIdx.x;
  const size_t total = (size_t)2 * G4 * KCAT;
  if (idx >= total) return;
  int cc = (int)(idx % KCAT);
  size_t rowidx = idx / KCAT;          // d*G4 + p
  int p  = (int)(rowidx % G4);
  int dd = (int)(rowidx / G4);
  int j  = p >> 2;
  int ty = p & 3;
  size_t rbase = (size_t)dd * G4 + (size_t)(ty * H_SZ + j);

  float w0;
  if (cc < MAXLEN)      w0 = w_ih0[rbase * MAXLEN + cc];
  else if (cc < KIH)    w0 = 0.f;                             // zero pad 1000..1023
  else                  w0 = w_hh0[rbase * H_SZ + (cc - KIH)];
  unsigned short h0 = f2bf(w0);
  Bhi0[idx] = h0;
  Blo0[idx] = f2bf(w0 - bf2f(h0));

  float w1;
  if (cc < KIH)         w1 = w_ih1[rbase * KIH + cc];
  else                  w1 = w_hh1[rbase * H_SZ + (cc - KIH)];
  unsigned short h1 = f2bf(w1);
  Bhi1[idx] = h1;
  Blo1[idx] = f2bf(w1 - bf2f(h1));
}

__global__ void prep_b_kernel(const float* __restrict__ b_ih0,
                              const float* __restrict__ b_hh0,
                              const float* __restrict__ b_ih1,
                              const float* __restrict__ b_hh1,
                              float* __restrict__ bias0,
                              float* __restrict__ bias1) {
  int idx = blockIdx.x * blockDim.x + threadIdx.x;   // 0 .. 2*G4-1
  if (idx >= 2 * G4) return;
  int p  = idx % G4;
  int dd = idx / G4;
  int src = dd * G4 + (p & 3) * H_SZ + (p >> 2);
  bias0[idx] = b_ih0[src] + b_hh0[src];
  bias1[idx] = b_ih1[src] + b_hh1[src];
}

// ============================================================
// one recurrent step (both directions via blockIdx.z)
// 512 threads = 8 waves (4 wr x 2 wc); each wave: 2 M-tiles x 2 N-tiles.
// Block tile: BM=128 x BN=64; grid (32,16,2)=1024 blocks -> 4 blocks/CU,
// 32 waves/CU (100% occupancy cap).
// gates = [A_in | h] @ (Bhi+Blo)[d]^T + bias ;  LSTM cell fused in epilogue
// ============================================================
template <int LAYER>
__global__ __launch_bounds__(512, 8)
void step_kernel(const int* __restrict__ x,
                 const unsigned short* __restrict__ seq_in,   // [T,B,2H] bf16
                 const unsigned short* __restrict__ Bhi,      // [2,G4,KCAT] bf16
                 const unsigned short* __restrict__ Blo,      // [2,G4,KCAT] bf16
                 const float* __restrict__ bias,              // [2,G4] f32
                 const unsigned short* __restrict__ h_in,     // [2,B,H] bf16
                 unsigned short* __restrict__ h_out,          // [2,B,H] bf16
                 float* __restrict__ c_st,                    // [2,B,H] f32
                 unsigned short* __restrict__ seq_out,        // [T,B,2H]   (LAYER 0)
                 float* __restrict__ zacc,                    // [B,2H] f32 (LAYER 1)
                 const float* __restrict__ emb_w,             // [21] f32   (LAYER 1)
                 int step) {
  __shared__ union {
    struct {
      unsigned short A[BM * LDSK];    // 10 KB
      unsigned short Bh[BN * LDSK];   // 5 KB
      unsigned short Bl[BN * LDSK];   // 5 KB
    } t;
    float gc[BM * GPAD];              // 16.9 KB gates chunk (128 x 32 + pad)
  } sm;                               // union: 16.9 KB

  const int tid  = threadIdx.x;
  const int lane = tid & 63;
  const int wave = tid >> 6;          // 0..7
  const int wr   = wave >> 1;         // 0..3  (M: wr*32 + mt*16)
  const int wc   = wave & 1;          // 0..1  (N: wc*32 + nt*16)
  const int q    = lane >> 4;
  const int r16  = lane & 15;

  const int d    = blockIdx.z;
  const int tcur = d ? (TSTEPS - 1 - step) : step;
  const int n0   = blockIdx.x * BN;   // permuted gate cols
  const int m0   = blockIdx.y * BM;   // batch rows

  const unsigned short* Bh_mat = Bhi + (size_t)d * G4 * KCAT;
  const unsigned short* Bl_mat = Blo + (size_t)d * G4 * KCAT;

  float bval[2];
#pragma unroll
  for (int nt = 0; nt < 2; ++nt)
    bval[nt] = bias[d * G4 + n0 + wc * 32 + nt * 16 + r16];

  f32x4 acc[2][2];
#pragma unroll
  for (int mt = 0; mt < 2; ++mt)
#pragma unroll
    for (int nt = 0; nt < 2; ++nt) {
      f32x4 z = {0.f, 0.f, 0.f, 0.f};
      acc[mt][nt] = z;
    }

  // staging: A tile 128x32 = 512 chunks (1/thread); B hi/lo 64x32 = 256 each
  const int rA = tid >> 2;              // A row 0..127
  const int oA = (tid & 3) * 8;         // A k-offset
  const int tb = tid & 255;
  const int rB = tb >> 2;               // B row 0..63
  const int oB = (tb & 3) * 8;
  const bool isLo = (tid >> 8) != 0;    // threads 256..511 stage Bl

  for (int kt = 0; kt < KCAT / BK; ++kt) {
    const int k0 = kt * BK;

    // ---- global loads first (latency hiding) ----
    const unsigned short* bsrc = isLo ? Bl_mat : Bh_mat;
    ushort8 vb = *(const ushort8*)(bsrc + (size_t)(n0 + rB) * KCAT + k0 + oB);

    unsigned int pk[4];     // one-hot payload (8 k-values packed as 4 x uint32)
    ushort8 va;             // bf16 A payload
    const bool onehot = (LAYER == 0) && (k0 < KIH);
    if (onehot) {
      const int* xr = x + (size_t)(m0 + rA) * MAXLEN + k0 + oA;
#pragma unroll
      for (int e = 0; e < 4; ++e) {
        int kk = k0 + oA + 2 * e;
        int v0 = (kk < MAXLEN) ? xr[2 * e] : -1;
        int v1 = (kk + 1 < MAXLEN) ? xr[2 * e + 1] : -1;
        unsigned int lo = (v0 == tcur) ? 0x3F80u : 0u;   // bf16 1.0
        unsigned int hi = (v1 == tcur) ? 0x3F80u : 0u;
        pk[e] = lo | (hi << 16);
      }
    } else {
      const unsigned short* Asrc;
      int lda, kof;
      if (LAYER == 1 && k0 < KIH) {
        Asrc = seq_in + (size_t)tcur * B_SZ * (2 * H_SZ);
        lda = 2 * H_SZ; kof = k0;
      } else {
        Asrc = h_in + (size_t)d * B_SZ * H_SZ;
        lda = H_SZ; kof = k0 - KIH;
      }
      va = *(const ushort8*)(Asrc + (size_t)(m0 + rA) * lda + kof + oA);
    }

    __syncthreads();   // previous iteration's MFMA LDS reads complete

    if (onehot) {
      *(uint4*)(sm.t.A + rA * LDSK + oA) = make_uint4(pk[0], pk[1], pk[2], pk[3]);
    } else {
      *(ushort8*)(sm.t.A + rA * LDSK + oA) = va;
    }
    *(ushort8*)((isLo ? sm.t.Bl : sm.t.Bh) + rB * LDSK + oB) = vb;
    __syncthreads();

    // ---- MFMA: 2x2 16x16 tiles per wave, 2 products (B hi+lo split) ----
    // A/B fragment: m/n = lane&15, k = (lane>>4)*8 + j   [m89/m91 verified]
    bf16x8 af[2], bh[2], bl[2];
#pragma unroll
    for (int mt = 0; mt < 2; ++mt)
      af[mt] = *(const bf16x8*)(sm.t.A + (wr * 32 + mt * 16 + r16) * LDSK + q * 8);
#pragma unroll
    for (int nt = 0; nt < 2; ++nt) {
      bh[nt] = *(const bf16x8*)(sm.t.Bh + (wc * 32 + nt * 16 + r16) * LDSK + q * 8);
      bl[nt] = *(const bf16x8*)(sm.t.Bl + (wc * 32 + nt * 16 + r16) * LDSK + q * 8);
    }
#pragma unroll
    for (int mt = 0; mt < 2; ++mt)
#pragma unroll
      for (int nt = 0; nt < 2; ++nt) {
        acc[mt][nt] = __builtin_amdgcn_mfma_f32_16x16x32_bf16(af[mt], bh[nt], acc[mt][nt], 0, 0, 0);
        acc[mt][nt] = __builtin_amdgcn_mfma_f32_16x16x32_bf16(af[mt], bl[nt], acc[mt][nt], 0, 0, 0);
      }
  }
  __syncthreads();   // all MFMA LDS reads done before gates scratch overwrite

  // ---- epilogue: 2 chunks of 32 gate-cols through 128x33 LDS scratch ----
  // C/D layout: col = lane&15, row = (lane>>4)*4 + reg   [m89/m91 verified]
  const int jbase = blockIdx.x * 16;   // 16 hidden units per N-block (BN=64)
  const float ew = (LAYER == 1) ? emb_w[tcur] : 0.f;

#pragma unroll
  for (int cc2 = 0; cc2 < 2; ++cc2) {
    if (wc == cc2) {
#pragma unroll
      for (int nt = 0; nt < 2; ++nt)
#pragma unroll
        for (int mt = 0; mt < 2; ++mt)
#pragma unroll
          for (int r = 0; r < 4; ++r) {
            int ml = wr * 32 + mt * 16 + q * 4 + r;
            int nl = nt * 16 + r16;
            sm.gc[ml * GPAD + nl] = acc[mt][nt][r] + bval[nt];
          }
    }
    __syncthreads();

    // read: 1024 cells (128 rows x 8 col-quads), 2 per thread
#pragma unroll
    for (int it = 0; it < 2; ++it) {
      int cell = it * 512 + tid;
      int rl = cell >> 3;        // row 0..127
      int jq = cell & 7;         // col-quad within chunk
      const float4 g = *(const float4*)(&sm.gc[rl * GPAD + jq * 4]);
      float si = sigmoidf_(g.x);
      float sf = sigmoidf_(g.y);
      float tg = tanhf_(g.z);
      float so = sigmoidf_(g.w);
      int b = m0 + rl;
      int j = jbase + cc2 * 8 + jq;
      size_t cidx = ((size_t)d * B_SZ + b) * H_SZ + j;
      float cn = sf * c_st[cidx] + si * tg;
      float hv = so * tanhf_(cn);
      c_st[cidx] = cn;
      h_out[cidx] = f2bf(hv);
      if (LAYER == 0) {
        seq_out[((size_t)tcur * B_SZ + b) * (2 * H_SZ) + d * H_SZ + j] = f2bf(hv);
      } else {
        zacc[(size_t)b * (2 * H_SZ) + d * H_SZ + j] += ew * hv;
      }
    }
    __syncthreads();
  }
}

// ============================================================
// final: z[b,:] = zacc[b,:] + emb_b ; out = z @ fc_w^T + fc_b   (all f32)
// ============================================================
__global__ __launch_bounds__(256)
void final_kernel(const float* __restrict__ zacc,    // [B, 2H] f32
                  const float* __restrict__ emb_b,   // [1]
                  const float* __restrict__ fc_w,    // [10, 2H]
                  const float* __restrict__ fc_b,    // [10]
                  float* __restrict__ out) {         // [B, 10] f32
  const int b = blockIdx.x;
  const int tid = threadIdx.x;
  const int c0 = tid * 4;

  const float zb = emb_b[0];
  const float4 z4 = *(const float4*)(zacc + (size_t)b * (2 * H_SZ) + c0);
  float z0 = z4.x + zb, z1 = z4.y + zb, z2 = z4.z + zb, z3 = z4.w + zb;

  float part[NCLS];
#pragma unroll
  for (int nc = 0; nc < NCLS; ++nc) {
    const float4 f = *(const float4*)(fc_w + (size_t)nc * (2 * H_SZ) + c0);
    part[nc] = z0 * f.x + z1 * f.y + z2 * f.z + z3 * f.w;
  }
#pragma unroll
  for (int nc = 0; nc < NCLS; ++nc)
#pragma unroll
    for (int off2 = 32; off2 > 0; off2 >>= 1)
      part[nc] += __shfl_down(part[nc], off2);

  __shared__ float red[4][NCLS];
  if ((tid & 63) == 0) {
#pragma unroll
    for (int nc = 0; nc < NCLS; ++nc) red[tid >> 6][nc] = part[nc];
  }
  __syncthreads();
  if (tid < NCLS) {
    float s = red[0][tid] + red[1][tid] + red[2][tid] + red[3][tid] + fc_b[tid];
    out[b * NCLS + tid] = s;
  }
}

// ============================================================
extern "C" void kernel_launch(void* const* d_in, const int* in_sizes, int n_in,
                              void* d_out, int out_size, void* d_ws, size_t ws_size,
                              hipStream_t stream) {
  (void)in_sizes; (void)n_in; (void)out_size; (void)ws_size;

  const int*   x     = (const int*)d_in[0];
  const float* w_ih0 = (const float*)d_in[1];
  const float* w_hh0 = (const float*)d_in[2];
  const float* b_ih0 = (const float*)d_in[3];
  const float* b_hh0 = (const float*)d_in[4];
  const float* w_ih1 = (const float*)d_in[5];
  const float* w_hh1 = (const float*)d_in[6];
  const float* b_ih1 = (const float*)d_in[7];
  const float* b_hh1 = (const float*)d_in[8];
  const float* emb_w = (const float*)d_in[9];
  const float* emb_b = (const float*)d_in[10];
  const float* fc_w  = (const float*)d_in[11];
  const float* fc_b  = (const float*)d_in[12];

  // -------- workspace layout (~165 MB) --------
  char* ws = (char*)d_ws;
  size_t off = 0;
  auto alloc = [&](size_t bytes) -> void* {
    void* p = ws + off;
    off += (bytes + 255) & ~(size_t)255;
    return p;
  };
  const size_t bmat_b = (size_t)2 * G4 * KCAT * 2;              // 12.6 MB each
  const size_t h_b    = (size_t)2 * B_SZ * H_SZ * 2;            // 4.2 MB
  const size_t c_b    = (size_t)2 * B_SZ * H_SZ * 4;            // 8.4 MB
  const size_t seq_b  = (size_t)TSTEPS * B_SZ * (2 * H_SZ) * 2; // 88 MB
  const size_t z_b    = (size_t)B_SZ * (2 * H_SZ) * 4;          // 8.4 MB

  unsigned short* Bhi0 = (unsigned short*)alloc(bmat_b);
  unsigned short* Blo0 = (unsigned short*)alloc(bmat_b);
  unsigned short* Bhi1 = (unsigned short*)alloc(bmat_b);
  unsigned short* Blo1 = (unsigned short*)alloc(bmat_b);
  float*          bias0 = (float*)alloc((size_t)2 * G4 * 4);
  float*          bias1 = (float*)alloc((size_t)2 * G4 * 4);
  unsigned short* hA    = (unsigned short*)alloc(h_b);
  unsigned short* hB    = (unsigned short*)alloc(h_b);
  float*          cst   = (float*)alloc(c_b);
  float*          zacc  = (float*)alloc(z_b);
  unsigned short* seq0  = (unsigned short*)alloc(seq_b);

  // -------- prep --------
  {
    size_t total = (size_t)2 * G4 * KCAT;
    int blocks = (int)((total + 255) / 256);
    prep_w_kernel<<<blocks, 256, 0, stream>>>(w_ih0, w_hh0, w_ih1, w_hh1,
                                              Bhi0, Blo0, Bhi1, Blo1);
    prep_b_kernel<<<16, 256, 0, stream>>>(b_ih0, b_hh0, b_ih1, b_hh1, bias0, bias1);
  }

  dim3 grid(G4 / BN, B_SZ / BM, 2);   // (32, 16, 2) = 1024 blocks

  // -------- layer 0 --------
  hipMemsetAsync(hA, 0, h_b, stream);
  hipMemsetAsync(cst, 0, c_b, stream);
  for (int s = 0; s < TSTEPS; ++s) {
    const unsigned short* hin  = (s & 1) ? hB : hA;
    unsigned short*       hout = (s & 1) ? hA : hB;
    step_kernel<0><<<grid, 512, 0, stream>>>(x, nullptr, Bhi0, Blo0, bias0, hin, hout, cst,
                                             seq0, nullptr, nullptr, s);
  }

  // -------- layer 1 (emb contraction fused into epilogue) --------
  hipMemsetAsync(hA, 0, h_b, stream);
  hipMemsetAsync(cst, 0, c_b, stream);
  hipMemsetAsync(zacc, 0, z_b, stream);
  for (int s = 0; s < TSTEPS; ++s) {
    const unsigned short* hin  = (s & 1) ? hB : hA;
    unsigned short*       hout = (s & 1) ? hA : hB;
    step_kernel<1><<<grid, 512, 0, stream>>>(nullptr, seq0, Bhi1, Blo1, bias1, hin, hout, cst,
                                             nullptr, zacc, emb_w, s);
  }

  // -------- fc --------
  final_kernel<<<B_SZ, 256, 0, stream>>>(zacc, emb_b, fc_w, fc_b, (float*)d_out);
}

// Round 7
// 5812.105 us; speedup vs baseline: 1.5306x; 1.5306x over previous
//
#include <hip/hip_runtime.h>
#include <hip/hip_bf16.h>
#include <cstdint>
#include <cstddef>

// ---------------- model dims ----------------
#define B_SZ    2048
#define H_SZ    512
#define G4      2048      // 4*H
#define TSTEPS  21
#define MAXLEN  1000
#define KIH     1024      // padded input-K (layer0: 1000->1024 ; layer1: 2H=1024)
#define KCAT    1536      // KIH + H_SZ
#define NCLS    10

// ---------------- GEMM tile ----------------
#define BM 128
#define BN 128
#define BK 32
#define LDSK 40           // padded LDS K-stride (elements); 80 B keeps 16B alignment
#define GPAD 33           // gates chunk stride (floats)

typedef short bf16x8 __attribute__((ext_vector_type(8)));            // 8 bf16 (4 VGPRs)
typedef float f32x4  __attribute__((ext_vector_type(4)));
typedef unsigned short ushort8 __attribute__((ext_vector_type(8)));  // 16B vector

__device__ __forceinline__ unsigned short f2bf(float f) {
  __hip_bfloat16 h = __float2bfloat16(f);
  unsigned short u;
  __builtin_memcpy(&u, &h, sizeof(u));
  return u;
}
__device__ __forceinline__ float bf2f(unsigned short u) {
  __hip_bfloat16 h;
  __builtin_memcpy(&h, &u, sizeof(h));
  return __bfloat162float(h);
}

__device__ __forceinline__ float sigmoidf_(float x) {
  x = fminf(fmaxf(x, -30.f), 30.f);
  return 1.f / (1.f + __expf(-x));
}
__device__ __forceinline__ float tanhf_(float x) {
  float xc = fminf(fmaxf(x, -15.f), 15.f);
  float e = __expf(2.f * xc);
  return (e - 1.f) / (e + 1.f);
}

// ============================================================
// prep: pack B[d][p][c] = [W_ih (padded to KIH) | W_hh], rows permuted,
// SPLIT into bf16 hi + lo (w ≈ hi + lo, ~16 mantissa bits).
// p = 4*j + type  <->  orig gate row r = type*512 + j   (i,f,g,o order)
// NOTE: the lo part is only CONSUMED for the recurrent columns (c >= KIH);
// input-projection rounding residuals are statistically negligible (see R7 notes).
// ============================================================
__global__ void prep_w_kernel(const float* __restrict__ w_ih0,
                              const float* __restrict__ w_hh0,
                              const float* __restrict__ w_ih1,
                              const float* __restrict__ w_hh1,
                              unsigned short* __restrict__ Bhi0,
                              unsigned short* __restrict__ Blo0,
                              unsigned short* __restrict__ Bhi1,
                              unsigned short* __restrict__ Blo1) {
  size_t idx = (size_t)blockIdx.x * blockDim.x + threadIdx.x;
  const size_t total = (size_t)2 * G4 * KCAT;
  if (idx >= total) return;
  int cc = (int)(idx % KCAT);
  size_t rowidx = idx / KCAT;          // d*G4 + p
  int p  = (int)(rowidx % G4);
  int dd = (int)(rowidx / G4);
  int j  = p >> 2;
  int ty = p & 3;
  size_t rbase = (size_t)dd * G4 + (size_t)(ty * H_SZ + j);

  float w0;
  if (cc < MAXLEN)      w0 = w_ih0[rbase * MAXLEN + cc];
  else if (cc < KIH)    w0 = 0.f;                             // zero pad 1000..1023
  else                  w0 = w_hh0[rbase * H_SZ + (cc - KIH)];
  unsigned short h0 = f2bf(w0);
  Bhi0[idx] = h0;
  Blo0[idx] = f2bf(w0 - bf2f(h0));

  float w1;
  if (cc < KIH)         w1 = w_ih1[rbase * KIH + cc];
  else                  w1 = w_hh1[rbase * H_SZ + (cc - KIH)];
  unsigned short h1 = f2bf(w1);
  Bhi1[idx] = h1;
  Blo1[idx] = f2bf(w1 - bf2f(h1));
}

__global__ void prep_b_kernel(const float* __restrict__ b_ih0,
                              const float* __restrict__ b_hh0,
                              const float* __restrict__ b_ih1,
                              const float* __restrict__ b_hh1,
                              float* __restrict__ bias0,
                              float* __restrict__ bias1) {
  int idx = blockIdx.x * blockDim.x + threadIdx.x;   // 0 .. 2*G4-1
  if (idx >= 2 * G4) return;
  int p  = idx % G4;
  int dd = idx / G4;
  int src = dd * G4 + (p & 3) * H_SZ + (p >> 2);
  bias0[idx] = b_ih0[src] + b_hh0[src];
  bias1[idx] = b_ih1[src] + b_hh1[src];
}

// ============================================================
// one recurrent step (both directions via blockIdx.z)
// 512 threads = 8 waves (4 wr x 2 wc); each wave: 2 M-tiles x 4 N-tiles.
// gates = [A_in | h] @ (Bhi [+ Blo for k>=KIH])[d]^T + bias ; cell fused.
// ============================================================
template <int LAYER>
__global__ __launch_bounds__(512, 4)
void step_kernel(const int* __restrict__ x,
                 const unsigned short* __restrict__ seq_in,   // [T,B,2H] bf16
                 const unsigned short* __restrict__ Bhi,      // [2,G4,KCAT] bf16
                 const unsigned short* __restrict__ Blo,      // [2,G4,KCAT] bf16
                 const float* __restrict__ bias,              // [2,G4] f32
                 const unsigned short* __restrict__ h_in,     // [2,B,H] bf16
                 unsigned short* __restrict__ h_out,          // [2,B,H] bf16
                 float* __restrict__ c_st,                    // [2,B,H] f32
                 unsigned short* __restrict__ seq_out,        // [T,B,2H]   (LAYER 0)
                 float* __restrict__ zacc,                    // [B,2H] f32 (LAYER 1)
                 const float* __restrict__ emb_w,             // [21] f32   (LAYER 1)
                 int step) {
  __shared__ union {
    struct {
      unsigned short A[BM * LDSK];    // 10 KB
      unsigned short Bh[BN * LDSK];   // 10 KB
      unsigned short Bl[BN * LDSK];   // 10 KB
    } t;
    float gc[BM * GPAD];              // 16.9 KB gates chunk (128 x 32 + pad)
  } sm;                               // union: 30 KB

  const int tid  = threadIdx.x;
  const int lane = tid & 63;
  const int wave = tid >> 6;          // 0..7
  const int wr   = wave >> 1;         // 0..3  (M: wr*32 + mt*16)
  const int wc   = wave & 1;          // 0..1  (N: wc*64 + nt*16)
  const int q    = lane >> 4;
  const int r16  = lane & 15;

  const int d    = blockIdx.z;
  const int tcur = d ? (TSTEPS - 1 - step) : step;
  const int n0   = blockIdx.x * BN;   // permuted gate cols
  const int m0   = blockIdx.y * BM;   // batch rows

  const unsigned short* Bh_mat = Bhi + (size_t)d * G4 * KCAT;
  const unsigned short* Bl_mat = Blo + (size_t)d * G4 * KCAT;

  float bval[4];
#pragma unroll
  for (int nt = 0; nt < 4; ++nt)
    bval[nt] = bias[d * G4 + n0 + wc * 64 + nt * 16 + r16];

  f32x4 acc[2][4];
#pragma unroll
  for (int mt = 0; mt < 2; ++mt)
#pragma unroll
    for (int nt = 0; nt < 4; ++nt) {
      f32x4 z = {0.f, 0.f, 0.f, 0.f};
      acc[mt][nt] = z;
    }

  // staging: 512 chunks of 8 elts per [128 x 32] tile; 1 chunk/thread
  const int rstg = tid >> 2;            // tile row 0..127
  const int ostg = (tid & 3) * 8;       // k offset 0/8/16/24

  for (int kt = 0; kt < KCAT / BK; ++kt) {
    const int k0 = kt * BK;
    const bool useLo = (k0 >= KIH);     // lo-product only for recurrent columns

    // ---- global loads first (latency hiding) ----
    ushort8 bh0 = *(const ushort8*)(Bh_mat + (size_t)(n0 + rstg) * KCAT + k0 + ostg);
    ushort8 bl0;
    if (useLo)
      bl0 = *(const ushort8*)(Bl_mat + (size_t)(n0 + rstg) * KCAT + k0 + ostg);

    unsigned int pk[4];     // one-hot payload (8 k-values packed as 4 x uint32)
    ushort8 va0;            // bf16 A payload
    const bool onehot = (LAYER == 0) && (k0 < KIH);
    if (onehot) {
      const int* xr = x + (size_t)(m0 + rstg) * MAXLEN + k0 + ostg;
#pragma unroll
      for (int e = 0; e < 4; ++e) {
        int kk = k0 + ostg + 2 * e;
        int v0 = (kk < MAXLEN) ? xr[2 * e] : -1;
        int v1 = (kk + 1 < MAXLEN) ? xr[2 * e + 1] : -1;
        unsigned int lo = (v0 == tcur) ? 0x3F80u : 0u;   // bf16 1.0
        unsigned int hi = (v1 == tcur) ? 0x3F80u : 0u;
        pk[e] = lo | (hi << 16);
      }
    } else {
      const unsigned short* Asrc;
      int lda, kof;
      if (LAYER == 1 && k0 < KIH) {
        Asrc = seq_in + (size_t)tcur * B_SZ * (2 * H_SZ);
        lda = 2 * H_SZ; kof = k0;
      } else {
        Asrc = h_in + (size_t)d * B_SZ * H_SZ;
        lda = H_SZ; kof = k0 - KIH;
      }
      va0 = *(const ushort8*)(Asrc + (size_t)(m0 + rstg) * lda + kof + ostg);
    }

    __syncthreads();   // previous iteration's MFMA LDS reads complete

    if (onehot) {
      *(uint4*)(sm.t.A + rstg * LDSK + ostg) = make_uint4(pk[0], pk[1], pk[2], pk[3]);
    } else {
      *(ushort8*)(sm.t.A + rstg * LDSK + ostg) = va0;
    }
    *(ushort8*)(sm.t.Bh + rstg * LDSK + ostg) = bh0;
    if (useLo)
      *(ushort8*)(sm.t.Bl + rstg * LDSK + ostg) = bl0;
    __syncthreads();

    // ---- MFMA: 2x4 16x16 tiles per wave; +lo product on recurrent k ----
    // A/B fragment: m/n = lane&15, k = (lane>>4)*8 + j   [m89/m91 verified]
    bf16x8 af[2], bh[4];
#pragma unroll
    for (int mt = 0; mt < 2; ++mt)
      af[mt] = *(const bf16x8*)(sm.t.A + (wr * 32 + mt * 16 + r16) * LDSK + q * 8);
#pragma unroll
    for (int nt = 0; nt < 4; ++nt)
      bh[nt] = *(const bf16x8*)(sm.t.Bh + (wc * 64 + nt * 16 + r16) * LDSK + q * 8);
#pragma unroll
    for (int mt = 0; mt < 2; ++mt)
#pragma unroll
      for (int nt = 0; nt < 4; ++nt)
        acc[mt][nt] = __builtin_amdgcn_mfma_f32_16x16x32_bf16(af[mt], bh[nt], acc[mt][nt], 0, 0, 0);
    if (useLo) {
      bf16x8 bl[4];
#pragma unroll
      for (int nt = 0; nt < 4; ++nt)
        bl[nt] = *(const bf16x8*)(sm.t.Bl + (wc * 64 + nt * 16 + r16) * LDSK + q * 8);
#pragma unroll
      for (int mt = 0; mt < 2; ++mt)
#pragma unroll
        for (int nt = 0; nt < 4; ++nt)
          acc[mt][nt] = __builtin_amdgcn_mfma_f32_16x16x32_bf16(af[mt], bl[nt], acc[mt][nt], 0, 0, 0);
    }
  }
  __syncthreads();   // all MFMA LDS reads done before gates scratch overwrite

  // ---- epilogue: 4 chunks of 32 gate-cols through 128x33 LDS scratch ----
  // C/D layout: col = lane&15, row = (lane>>4)*4 + reg   [m89/m91 verified]
  const int jbase = blockIdx.x * 32;   // 32 hidden units per N-block
  const float ew = (LAYER == 1) ? emb_w[tcur] : 0.f;

#pragma unroll
  for (int cc2 = 0; cc2 < 4; ++cc2) {
    if (wc == (cc2 >> 1)) {
      const int ntb = (cc2 & 1) * 2;
#pragma unroll
      for (int nti = 0; nti < 2; ++nti) {
        const int nt = ntb + nti;
#pragma unroll
        for (int mt = 0; mt < 2; ++mt)
#pragma unroll
          for (int r = 0; r < 4; ++r) {
            int ml = wr * 32 + mt * 16 + q * 4 + r;
            int nl = nti * 16 + r16;
            sm.gc[ml * GPAD + nl] = acc[mt][nt][r] + bval[nt];
          }
      }
    }
    __syncthreads();

    // read: 1024 cells (128 rows x 8 col-quads), 2 per thread
#pragma unroll
    for (int it = 0; it < 2; ++it) {
      int cell = it * 512 + tid;
      int rl = cell >> 3;        // row 0..127
      int jq = cell & 7;         // col-quad within chunk
      const float4 g = *(const float4*)(&sm.gc[rl * GPAD + jq * 4]);
      float si = sigmoidf_(g.x);
      float sf = sigmoidf_(g.y);
      float tg = tanhf_(g.z);
      float so = sigmoidf_(g.w);
      int b = m0 + rl;
      int j = jbase + cc2 * 8 + jq;
      size_t cidx = ((size_t)d * B_SZ + b) * H_SZ + j;
      float cn = sf * c_st[cidx] + si * tg;
      float hv = so * tanhf_(cn);
      c_st[cidx] = cn;
      h_out[cidx] = f2bf(hv);
      if (LAYER == 0) {
        seq_out[((size_t)tcur * B_SZ + b) * (2 * H_SZ) + d * H_SZ + j] = f2bf(hv);
      } else {
        zacc[(size_t)b * (2 * H_SZ) + d * H_SZ + j] += ew * hv;
      }
    }
    __syncthreads();
  }
}

// ============================================================
// final: z[b,:] = zacc[b,:] + emb_b ; out = z @ fc_w^T + fc_b   (all f32)
// ============================================================
__global__ __launch_bounds__(256)
void final_kernel(const float* __restrict__ zacc,    // [B, 2H] f32
                  const float* __restrict__ emb_b,   // [1]
                  const float* __restrict__ fc_w,    // [10, 2H]
                  const float* __restrict__ fc_b,    // [10]
                  float* __restrict__ out) {         // [B, 10] f32
  const int b = blockIdx.x;
  const int tid = threadIdx.x;
  const int c0 = tid * 4;

  const float zb = emb_b[0];
  const float4 z4 = *(const float4*)(zacc + (size_t)b * (2 * H_SZ) + c0);
  float z0 = z4.x + zb, z1 = z4.y + zb, z2 = z4.z + zb, z3 = z4.w + zb;

  float part[NCLS];
#pragma unroll
  for (int nc = 0; nc < NCLS; ++nc) {
    const float4 f = *(const float4*)(fc_w + (size_t)nc * (2 * H_SZ) + c0);
    part[nc] = z0 * f.x + z1 * f.y + z2 * f.z + z3 * f.w;
  }
#pragma unroll
  for (int nc = 0; nc < NCLS; ++nc)
#pragma unroll
    for (int off2 = 32; off2 > 0; off2 >>= 1)
      part[nc] += __shfl_down(part[nc], off2);

  __shared__ float red[4][NCLS];
  if ((tid & 63) == 0) {
#pragma unroll
    for (int nc = 0; nc < NCLS; ++nc) red[tid >> 6][nc] = part[nc];
  }
  __syncthreads();
  if (tid < NCLS) {
    float s = red[0][tid] + red[1][tid] + red[2][tid] + red[3][tid] + fc_b[tid];
    out[b * NCLS + tid] = s;
  }
}

// ============================================================
extern "C" void kernel_launch(void* const* d_in, const int* in_sizes, int n_in,
                              void* d_out, int out_size, void* d_ws, size_t ws_size,
                              hipStream_t stream) {
  (void)in_sizes; (void)n_in; (void)out_size; (void)ws_size;

  const int*   x     = (const int*)d_in[0];
  const float* w_ih0 = (const float*)d_in[1];
  const float* w_hh0 = (const float*)d_in[2];
  const float* b_ih0 = (const float*)d_in[3];
  const float* b_hh0 = (const float*)d_in[4];
  const float* w_ih1 = (const float*)d_in[5];
  const float* w_hh1 = (const float*)d_in[6];
  const float* b_ih1 = (const float*)d_in[7];
  const float* b_hh1 = (const float*)d_in[8];
  const float* emb_w = (const float*)d_in[9];
  const float* emb_b = (const float*)d_in[10];
  const float* fc_w  = (const float*)d_in[11];
  const float* fc_b  = (const float*)d_in[12];

  // -------- workspace layout (~165 MB) --------
  char* ws = (char*)d_ws;
  size_t off = 0;
  auto alloc = [&](size_t bytes) -> void* {
    void* p = ws + off;
    off += (bytes + 255) & ~(size_t)255;
    return p;
  };
  const size_t bmat_b = (size_t)2 * G4 * KCAT * 2;              // 12.6 MB each
  const size_t h_b    = (size_t)2 * B_SZ * H_SZ * 2;            // 4.2 MB
  const size_t c_b    = (size_t)2 * B_SZ * H_SZ * 4;            // 8.4 MB
  const size_t seq_b  = (size_t)TSTEPS * B_SZ * (2 * H_SZ) * 2; // 88 MB
  const size_t z_b    = (size_t)B_SZ * (2 * H_SZ) * 4;          // 8.4 MB

  unsigned short* Bhi0 = (unsigned short*)alloc(bmat_b);
  unsigned short* Blo0 = (unsigned short*)alloc(bmat_b);
  unsigned short* Bhi1 = (unsigned short*)alloc(bmat_b);
  unsigned short* Blo1 = (unsigned short*)alloc(bmat_b);
  float*          bias0 = (float*)alloc((size_t)2 * G4 * 4);
  float*          bias1 = (float*)alloc((size_t)2 * G4 * 4);
  unsigned short* hA    = (unsigned short*)alloc(h_b);
  unsigned short* hB    = (unsigned short*)alloc(h_b);
  float*          cst   = (float*)alloc(c_b);
  float*          zacc  = (float*)alloc(z_b);
  unsigned short* seq0  = (unsigned short*)alloc(seq_b);

  // -------- prep --------
  {
    size_t total = (size_t)2 * G4 * KCAT;
    int blocks = (int)((total + 255) / 256);
    prep_w_kernel<<<blocks, 256, 0, stream>>>(w_ih0, w_hh0, w_ih1, w_hh1,
                                              Bhi0, Blo0, Bhi1, Blo1);
    prep_b_kernel<<<16, 256, 0, stream>>>(b_ih0, b_hh0, b_ih1, b_hh1, bias0, bias1);
  }

  dim3 grid(G4 / BN, B_SZ / BM, 2);   // (16, 16, 2) = 512 blocks

  // -------- layer 0 --------
  hipMemsetAsync(hA, 0, h_b, stream);
  hipMemsetAsync(cst, 0, c_b, stream);
  for (int s = 0; s < TSTEPS; ++s) {
    const unsigned short* hin  = (s & 1) ? hB : hA;
    unsigned short*       hout = (s & 1) ? hA : hB;
    step_kernel<0><<<grid, 512, 0, stream>>>(x, nullptr, Bhi0, Blo0, bias0, hin, hout, cst,
                                             seq0, nullptr, nullptr, s);
  }

  // -------- layer 1 (emb contraction fused into epilogue) --------
  hipMemsetAsync(hA, 0, h_b, stream);
  hipMemsetAsync(cst, 0, c_b, stream);
  hipMemsetAsync(zacc, 0, z_b, stream);
  for (int s = 0; s < TSTEPS; ++s) {
    const unsigned short* hin  = (s & 1) ? hB : hA;
    unsigned short*       hout = (s & 1) ? hA : hB;
    step_kernel<1><<<grid, 512, 0, stream>>>(nullptr, seq0, Bhi1, Blo1, bias1, hin, hout, cst,
                                             nullptr, zacc, emb_w, s);
  }

  // -------- fc --------
  final_kernel<<<B_SZ, 256, 0, stream>>>(zacc, emb_b, fc_w, fc_b, (float*)d_out);
}

// Round 8
// 5682.501 us; speedup vs baseline: 1.5655x; 1.0228x over previous
//
#include <hip/hip_runtime.h>
#include <hip/hip_bf16.h>
#include <cstdint>
#include <cstddef>

// ---------------- model dims ----------------
#define B_SZ    2048
#define H_SZ    512
#define G4      2048      // 4*H
#define TSTEPS  21
#define MAXLEN  1000
#define KIH     1024      // padded input-K (layer0: 1000->1024 ; layer1: 2H=1024)
#define KCAT    1536      // KIH + H_SZ
#define NCLS    10
#define NIT     (KCAT / BK)

// ---------------- GEMM tile ----------------
#define BM 128
#define BN 128
#define BK 32
#define LDSK 40           // padded LDS K-stride (elements); 80 B keeps 16B alignment
#define GPAD 33           // gates chunk stride (floats)

typedef short bf16x8 __attribute__((ext_vector_type(8)));            // 8 bf16 (4 VGPRs)
typedef float f32x4  __attribute__((ext_vector_type(4)));
typedef unsigned short ushort8 __attribute__((ext_vector_type(8)));  // 16B vector

__device__ __forceinline__ unsigned short f2bf(float f) {
  __hip_bfloat16 h = __float2bfloat16(f);
  unsigned short u;
  __builtin_memcpy(&u, &h, sizeof(u));
  return u;
}
__device__ __forceinline__ float bf2f(unsigned short u) {
  __hip_bfloat16 h;
  __builtin_memcpy(&h, &u, sizeof(h));
  return __bfloat162float(h);
}

__device__ __forceinline__ float sigmoidf_(float x) {
  x = fminf(fmaxf(x, -30.f), 30.f);
  return 1.f / (1.f + __expf(-x));
}
__device__ __forceinline__ float tanhf_(float x) {
  float xc = fminf(fmaxf(x, -15.f), 15.f);
  float e = __expf(2.f * xc);
  return (e - 1.f) / (e + 1.f);
}

// ============================================================
// prep: pack B[d][p][c] = [W_ih (padded to KIH) | W_hh], rows permuted,
// SPLIT into bf16 hi + lo (w ≈ hi + lo). lo consumed only for c >= KIH.
// p = 4*j + type  <->  orig gate row r = type*512 + j   (i,f,g,o order)
// ============================================================
__global__ void prep_w_kernel(const float* __restrict__ w_ih0,
                              const float* __restrict__ w_hh0,
                              const float* __restrict__ w_ih1,
                              const float* __restrict__ w_hh1,
                              unsigned short* __restrict__ Bhi0,
                              unsigned short* __restrict__ Blo0,
                              unsigned short* __restrict__ Bhi1,
                              unsigned short* __restrict__ Blo1) {
  size_t idx = (size_t)blockIdx.x * blockDim.x + threadIdx.x;
  const size_t total = (size_t)2 * G4 * KCAT;
  if (idx >= total) return;
  int cc = (int)(idx % KCAT);
  size_t rowidx = idx / KCAT;          // d*G4 + p
  int p  = (int)(rowidx % G4);
  int dd = (int)(rowidx / G4);
  int j  = p >> 2;
  int ty = p & 3;
  size_t rbase = (size_t)dd * G4 + (size_t)(ty * H_SZ + j);

  float w0;
  if (cc < MAXLEN)      w0 = w_ih0[rbase * MAXLEN + cc];
  else if (cc < KIH)    w0 = 0.f;                             // zero pad 1000..1023
  else                  w0 = w_hh0[rbase * H_SZ + (cc - KIH)];
  unsigned short h0 = f2bf(w0);
  Bhi0[idx] = h0;
  Blo0[idx] = f2bf(w0 - bf2f(h0));

  float w1;
  if (cc < KIH)         w1 = w_ih1[rbase * KIH + cc];
  else                  w1 = w_hh1[rbase * H_SZ + (cc - KIH)];
  unsigned short h1 = f2bf(w1);
  Bhi1[idx] = h1;
  Blo1[idx] = f2bf(w1 - bf2f(h1));
}

__global__ void prep_b_kernel(const float* __restrict__ b_ih0,
                              const float* __restrict__ b_hh0,
                              const float* __restrict__ b_ih1,
                              const float* __restrict__ b_hh1,
                              float* __restrict__ bias0,
                              float* __restrict__ bias1) {
  int idx = blockIdx.x * blockDim.x + threadIdx.x;   // 0 .. 2*G4-1
  if (idx >= 2 * G4) return;
  int p  = idx % G4;
  int dd = idx / G4;
  int src = dd * G4 + (p & 3) * H_SZ + (p >> 2);
  bias0[idx] = b_ih0[src] + b_hh0[src];
  bias1[idx] = b_ih1[src] + b_hh1[src];
}

// ============================================================
// one recurrent step. 1D grid of 512 blocks, XCD-swizzled decode:
//   xcd = bid & 7 owns n-slices {2*xcd, 2*xcd+1} (x2 dirs ~2.6 MB hi+lo -> fits 4MB L2)
// 512 threads = 8 waves (4 wr x 2 wc); wave: 2 M-tiles x 4 N-tiles.
// K-loop software-pipelined: iter k+1's global loads issued before iter k's MFMA.
// gates = [A_in | h] @ (Bhi [+ Blo for k>=KIH])^T + bias ; LSTM cell fused.
// ============================================================
template <int LAYER>
__global__ __launch_bounds__(512, 4)
void step_kernel(const int* __restrict__ x,
                 const unsigned short* __restrict__ seq_in,   // [T,B,2H] bf16
                 const unsigned short* __restrict__ Bhi,      // [2,G4,KCAT] bf16
                 const unsigned short* __restrict__ Blo,      // [2,G4,KCAT] bf16
                 const float* __restrict__ bias,              // [2,G4] f32
                 const unsigned short* __restrict__ h_in,     // [2,B,H] bf16
                 unsigned short* __restrict__ h_out,          // [2,B,H] bf16
                 float* __restrict__ c_st,                    // [2,B,H] f32
                 unsigned short* __restrict__ seq_out,        // [T,B,2H]   (LAYER 0)
                 float* __restrict__ zacc,                    // [B,2H] f32 (LAYER 1)
                 const float* __restrict__ emb_w,             // [21] f32   (LAYER 1)
                 int step) {
  __shared__ union {
    struct {
      unsigned short A[BM * LDSK];    // 10 KB
      unsigned short Bh[BN * LDSK];   // 10 KB
      unsigned short Bl[BN * LDSK];   // 10 KB
    } t;
    float gc[BM * GPAD];              // 16.9 KB gates chunk (128 x 32 + pad)
  } sm;                               // union: 30 KB

  const int tid  = threadIdx.x;
  const int lane = tid & 63;
  const int wave = tid >> 6;          // 0..7
  const int wr   = wave >> 1;         // 0..3  (M: wr*32 + mt*16)
  const int wc   = wave & 1;          // 0..1  (N: wc*64 + nt*16)
  const int q    = lane >> 4;
  const int r16  = lane & 15;

  // ---- XCD-swizzled block decode: bid = slot<<3 | xcd ----
  const int bid  = blockIdx.x;        // 0..511
  const int xcd  = bid & 7;
  const int slot = bid >> 3;          // 0..63 = d*32 + mb*2 + nsub
  const int nb   = xcd * 2 + (slot & 1);    // 0..15 n-block (pinned per XCD)
  const int mb   = (slot >> 1) & 15;        // 0..15 m-block
  const int d    = slot >> 5;               // direction

  const int tcur = d ? (TSTEPS - 1 - step) : step;
  const int n0   = nb * BN;           // permuted gate cols
  const int m0   = mb * BM;           // batch rows

  const unsigned short* Bh_mat = Bhi + (size_t)d * G4 * KCAT;
  const unsigned short* Bl_mat = Blo + (size_t)d * G4 * KCAT;

  float bval[4];
#pragma unroll
  for (int nt = 0; nt < 4; ++nt)
    bval[nt] = bias[d * G4 + n0 + wc * 64 + nt * 16 + r16];

  f32x4 acc[2][4];
#pragma unroll
  for (int mt = 0; mt < 2; ++mt)
#pragma unroll
    for (int nt = 0; nt < 4; ++nt) {
      f32x4 z = {0.f, 0.f, 0.f, 0.f};
      acc[mt][nt] = z;
    }

  // staging: 512 chunks of 8 elts per [128 x 32] tile; 1 chunk/thread
  const int rstg = tid >> 2;            // tile row 0..127
  const int ostg = (tid & 3) * 8;       // k offset 0/8/16/24

  // ---- prefetch payload registers ----
  ushort8 vbh, vbl, va;
  int xv[8];

  auto load_iter = [&](int kt) {
    const int k0 = kt * BK;
    vbh = *(const ushort8*)(Bh_mat + (size_t)(n0 + rstg) * KCAT + k0 + ostg);
    if (k0 >= KIH)
      vbl = *(const ushort8*)(Bl_mat + (size_t)(n0 + rstg) * KCAT + k0 + ostg);
    if (LAYER == 0 && k0 < KIH) {
      const int* xr = x + (size_t)(m0 + rstg) * MAXLEN + k0 + ostg;
#pragma unroll
      for (int e = 0; e < 8; ++e) {
        int kk = k0 + ostg + e;
        xv[e] = (kk < MAXLEN) ? xr[e] : -1;
      }
    } else {
      const unsigned short* Asrc;
      int lda, kof;
      if (LAYER == 1 && k0 < KIH) {
        Asrc = seq_in + (size_t)tcur * B_SZ * (2 * H_SZ);
        lda = 2 * H_SZ; kof = k0;
      } else {
        Asrc = h_in + (size_t)d * B_SZ * H_SZ;
        lda = H_SZ; kof = k0 - KIH;
      }
      va = *(const ushort8*)(Asrc + (size_t)(m0 + rstg) * lda + kof + ostg);
    }
  };

  load_iter(0);

  for (int kt = 0; kt < NIT; ++kt) {
    const int k0 = kt * BK;
    const bool useLo = (k0 >= KIH);
    const bool onehot = (LAYER == 0) && (k0 < KIH);

    __syncthreads();   // previous iteration's MFMA LDS reads complete

    // ---- store prefetched payload to LDS ----
    if (onehot) {
      unsigned int pk[4];
#pragma unroll
      for (int e = 0; e < 4; ++e) {
        unsigned int lo = (xv[2 * e]     == tcur) ? 0x3F80u : 0u;   // bf16 1.0
        unsigned int hi = (xv[2 * e + 1] == tcur) ? 0x3F80u : 0u;
        pk[e] = lo | (hi << 16);
      }
      *(uint4*)(sm.t.A + rstg * LDSK + ostg) = make_uint4(pk[0], pk[1], pk[2], pk[3]);
    } else {
      *(ushort8*)(sm.t.A + rstg * LDSK + ostg) = va;
    }
    *(ushort8*)(sm.t.Bh + rstg * LDSK + ostg) = vbh;
    if (useLo)
      *(ushort8*)(sm.t.Bl + rstg * LDSK + ostg) = vbl;
    __syncthreads();

    // ---- issue next iteration's global loads (overlap with MFMA below) ----
    if (kt + 1 < NIT) load_iter(kt + 1);

    // ---- MFMA: 2x4 16x16 tiles per wave; +lo product on recurrent k ----
    // A/B fragment: m/n = lane&15, k = (lane>>4)*8 + j   [m89/m91 verified]
    bf16x8 af[2], bh[4];
#pragma unroll
    for (int mt = 0; mt < 2; ++mt)
      af[mt] = *(const bf16x8*)(sm.t.A + (wr * 32 + mt * 16 + r16) * LDSK + q * 8);
#pragma unroll
    for (int nt = 0; nt < 4; ++nt)
      bh[nt] = *(const bf16x8*)(sm.t.Bh + (wc * 64 + nt * 16 + r16) * LDSK + q * 8);
#pragma unroll
    for (int mt = 0; mt < 2; ++mt)
#pragma unroll
      for (int nt = 0; nt < 4; ++nt)
        acc[mt][nt] = __builtin_amdgcn_mfma_f32_16x16x32_bf16(af[mt], bh[nt], acc[mt][nt], 0, 0, 0);
    if (useLo) {
      bf16x8 bl[4];
#pragma unroll
      for (int nt = 0; nt < 4; ++nt)
        bl[nt] = *(const bf16x8*)(sm.t.Bl + (wc * 64 + nt * 16 + r16) * LDSK + q * 8);
#pragma unroll
      for (int mt = 0; mt < 2; ++mt)
#pragma unroll
        for (int nt = 0; nt < 4; ++nt)
          acc[mt][nt] = __builtin_amdgcn_mfma_f32_16x16x32_bf16(af[mt], bl[nt], acc[mt][nt], 0, 0, 0);
    }
  }
  __syncthreads();   // all MFMA LDS reads done before gates scratch overwrite

  // ---- epilogue: 4 chunks of 32 gate-cols through 128x33 LDS scratch ----
  // C/D layout: col = lane&15, row = (lane>>4)*4 + reg   [m89/m91 verified]
  const int jbase = nb * 32;   // 32 hidden units per N-block
  const float ew = (LAYER == 1) ? emb_w[tcur] : 0.f;

#pragma unroll
  for (int cc2 = 0; cc2 < 4; ++cc2) {
    if (wc == (cc2 >> 1)) {
      const int ntb = (cc2 & 1) * 2;
#pragma unroll
      for (int nti = 0; nti < 2; ++nti) {
        const int nt = ntb + nti;
#pragma unroll
        for (int mt = 0; mt < 2; ++mt)
#pragma unroll
          for (int r = 0; r < 4; ++r) {
            int ml = wr * 32 + mt * 16 + q * 4 + r;
            int nl = nti * 16 + r16;
            sm.gc[ml * GPAD + nl] = acc[mt][nt][r] + bval[nt];
          }
      }
    }
    __syncthreads();

    // read: 1024 cells (128 rows x 8 col-quads), 2 per thread
#pragma unroll
    for (int it = 0; it < 2; ++it) {
      int cell = it * 512 + tid;
      int rl = cell >> 3;        // row 0..127
      int jq = cell & 7;         // col-quad within chunk
      const float4 g = *(const float4*)(&sm.gc[rl * GPAD + jq * 4]);
      float si = sigmoidf_(g.x);
      float sf = sigmoidf_(g.y);
      float tg = tanhf_(g.z);
      float so = sigmoidf_(g.w);
      int b = m0 + rl;
      int j = jbase + cc2 * 8 + jq;
      size_t cidx = ((size_t)d * B_SZ + b) * H_SZ + j;
      float cn = sf * c_st[cidx] + si * tg;
      float hv = so * tanhf_(cn);
      c_st[cidx] = cn;
      h_out[cidx] = f2bf(hv);
      if (LAYER == 0) {
        seq_out[((size_t)tcur * B_SZ + b) * (2 * H_SZ) + d * H_SZ + j] = f2bf(hv);
      } else {
        zacc[(size_t)b * (2 * H_SZ) + d * H_SZ + j] += ew * hv;
      }
    }
    __syncthreads();
  }
}

// ============================================================
// final: z[b,:] = zacc[b,:] + emb_b ; out = z @ fc_w^T + fc_b   (all f32)
// ============================================================
__global__ __launch_bounds__(256)
void final_kernel(const float* __restrict__ zacc,    // [B, 2H] f32
                  const float* __restrict__ emb_b,   // [1]
                  const float* __restrict__ fc_w,    // [10, 2H]
                  const float* __restrict__ fc_b,    // [10]
                  float* __restrict__ out) {         // [B, 10] f32
  const int b = blockIdx.x;
  const int tid = threadIdx.x;
  const int c0 = tid * 4;

  const float zb = emb_b[0];
  const float4 z4 = *(const float4*)(zacc + (size_t)b * (2 * H_SZ) + c0);
  float z0 = z4.x + zb, z1 = z4.y + zb, z2 = z4.z + zb, z3 = z4.w + zb;

  float part[NCLS];
#pragma unroll
  for (int nc = 0; nc < NCLS; ++nc) {
    const float4 f = *(const float4*)(fc_w + (size_t)nc * (2 * H_SZ) + c0);
    part[nc] = z0 * f.x + z1 * f.y + z2 * f.z + z3 * f.w;
  }
#pragma unroll
  for (int nc = 0; nc < NCLS; ++nc)
#pragma unroll
    for (int off2 = 32; off2 > 0; off2 >>= 1)
      part[nc] += __shfl_down(part[nc], off2);

  __shared__ float red[4][NCLS];
  if ((tid & 63) == 0) {
#pragma unroll
    for (int nc = 0; nc < NCLS; ++nc) red[tid >> 6][nc] = part[nc];
  }
  __syncthreads();
  if (tid < NCLS) {
    float s = red[0][tid] + red[1][tid] + red[2][tid] + red[3][tid] + fc_b[tid];
    out[b * NCLS + tid] = s;
  }
}

// ============================================================
extern "C" void kernel_launch(void* const* d_in, const int* in_sizes, int n_in,
                              void* d_out, int out_size, void* d_ws, size_t ws_size,
                              hipStream_t stream) {
  (void)in_sizes; (void)n_in; (void)out_size; (void)ws_size;

  const int*   x     = (const int*)d_in[0];
  const float* w_ih0 = (const float*)d_in[1];
  const float* w_hh0 = (const float*)d_in[2];
  const float* b_ih0 = (const float*)d_in[3];
  const float* b_hh0 = (const float*)d_in[4];
  const float* w_ih1 = (const float*)d_in[5];
  const float* w_hh1 = (const float*)d_in[6];
  const float* b_ih1 = (const float*)d_in[7];
  const float* b_hh1 = (const float*)d_in[8];
  const float* emb_w = (const float*)d_in[9];
  const float* emb_b = (const float*)d_in[10];
  const float* fc_w  = (const float*)d_in[11];
  const float* fc_b  = (const float*)d_in[12];

  // -------- workspace layout (~165 MB) --------
  char* ws = (char*)d_ws;
  size_t off = 0;
  auto alloc = [&](size_t bytes) -> void* {
    void* p = ws + off;
    off += (bytes + 255) & ~(size_t)255;
    return p;
  };
  const size_t bmat_b = (size_t)2 * G4 * KCAT * 2;              // 12.6 MB each
  const size_t h_b    = (size_t)2 * B_SZ * H_SZ * 2;            // 4.2 MB
  const size_t c_b    = (size_t)2 * B_SZ * H_SZ * 4;            // 8.4 MB
  const size_t seq_b  = (size_t)TSTEPS * B_SZ * (2 * H_SZ) * 2; // 88 MB
  const size_t z_b    = (size_t)B_SZ * (2 * H_SZ) * 4;          // 8.4 MB

  unsigned short* Bhi0 = (unsigned short*)alloc(bmat_b);
  unsigned short* Blo0 = (unsigned short*)alloc(bmat_b);
  unsigned short* Bhi1 = (unsigned short*)alloc(bmat_b);
  unsigned short* Blo1 = (unsigned short*)alloc(bmat_b);
  float*          bias0 = (float*)alloc((size_t)2 * G4 * 4);
  float*          bias1 = (float*)alloc((size_t)2 * G4 * 4);
  unsigned short* hA    = (unsigned short*)alloc(h_b);
  unsigned short* hB    = (unsigned short*)alloc(h_b);
  float*          cst   = (float*)alloc(c_b);
  float*          zacc  = (float*)alloc(z_b);
  unsigned short* seq0  = (unsigned short*)alloc(seq_b);

  // -------- prep --------
  {
    size_t total = (size_t)2 * G4 * KCAT;
    int blocks = (int)((total + 255) / 256);
    prep_w_kernel<<<blocks, 256, 0, stream>>>(w_ih0, w_hh0, w_ih1, w_hh1,
                                              Bhi0, Blo0, Bhi1, Blo1);
    prep_b_kernel<<<16, 256, 0, stream>>>(b_ih0, b_hh0, b_ih1, b_hh1, bias0, bias1);
  }

  const int nblocks = 512;   // 1D, XCD-swizzled decode inside kernel

  // -------- layer 0 --------
  hipMemsetAsync(hA, 0, h_b, stream);
  hipMemsetAsync(cst, 0, c_b, stream);
  for (int s = 0; s < TSTEPS; ++s) {
    const unsigned short* hin  = (s & 1) ? hB : hA;
    unsigned short*       hout = (s & 1) ? hA : hB;
    step_kernel<0><<<nblocks, 512, 0, stream>>>(x, nullptr, Bhi0, Blo0, bias0, hin, hout, cst,
                                                seq0, nullptr, nullptr, s);
  }

  // -------- layer 1 (emb contraction fused into epilogue) --------
  hipMemsetAsync(hA, 0, h_b, stream);
  hipMemsetAsync(cst, 0, c_b, stream);
  hipMemsetAsync(zacc, 0, z_b, stream);
  for (int s = 0; s < TSTEPS; ++s) {
    const unsigned short* hin  = (s & 1) ? hB : hA;
    unsigned short*       hout = (s & 1) ? hA : hB;
    step_kernel<1><<<nblocks, 512, 0, stream>>>(nullptr, seq0, Bhi1, Blo1, bias1, hin, hout, cst,
                                                nullptr, zacc, emb_w, s);
  }

  // -------- fc --------
  final_kernel<<<B_SZ, 256, 0, stream>>>(zacc, emb_b, fc_w, fc_b, (float*)d_out);
}

// Round 9
// 4852.505 us; speedup vs baseline: 1.8333x; 1.1710x over previous
//
#include <hip/hip_runtime.h>
#include <hip/hip_bf16.h>
#include <cstdint>
#include <cstddef>

// ---------------- model dims ----------------
#define B_SZ    2048
#define H_SZ    512
#define G4      2048      // 4*H
#define TSTEPS  21
#define MAXLEN  1000
#define KIH     1024      // padded input-K (layer0: 1000->1024 ; layer1: 2H=1024)
#define KCAT    1536      // KIH + H_SZ
#define NCLS    10

// ---------------- GEMM tile ----------------
#define BM 128
#define BN 128
#define BK 32
#define NIT  (KCAT / BK)  // 48 (even)
#define LDSK 40           // padded LDS K-stride (elements); 80 B keeps 16B alignment
#define GPAD 33           // gates chunk stride (floats)
#define XROW (KIH / 8)    // 128 bytes of one-hot bits per (t,b) row

typedef short bf16x8 __attribute__((ext_vector_type(8)));            // 8 bf16 (4 VGPRs)
typedef float f32x4  __attribute__((ext_vector_type(4)));
typedef unsigned short ushort8 __attribute__((ext_vector_type(8)));  // 16B vector

__device__ __forceinline__ unsigned short f2bf(float f) {
  __hip_bfloat16 h = __float2bfloat16(f);
  unsigned short u;
  __builtin_memcpy(&u, &h, sizeof(u));
  return u;
}
__device__ __forceinline__ float bf2f(unsigned short u) {
  __hip_bfloat16 h;
  __builtin_memcpy(&h, &u, sizeof(h));
  return __bfloat162float(h);
}

__device__ __forceinline__ float sigmoidf_(float x) {
  x = fminf(fmaxf(x, -30.f), 30.f);
  return 1.f / (1.f + __expf(-x));
}
__device__ __forceinline__ float tanhf_(float x) {
  float xc = fminf(fmaxf(x, -15.f), 15.f);
  float e = __expf(2.f * xc);
  return (e - 1.f) / (e + 1.f);
}

// ============================================================
// prep: pack B[d][p][c] = [W_ih (padded to KIH) | W_hh], rows permuted,
// SPLIT into bf16 hi + lo (w ≈ hi + lo). lo consumed only for c >= KIH.
// p = 4*j + type  <->  orig gate row r = type*512 + j   (i,f,g,o order)
// ============================================================
__global__ void prep_w_kernel(const float* __restrict__ w_ih0,
                              const float* __restrict__ w_hh0,
                              const float* __restrict__ w_ih1,
                              const float* __restrict__ w_hh1,
                              unsigned short* __restrict__ Bhi0,
                              unsigned short* __restrict__ Blo0,
                              unsigned short* __restrict__ Bhi1,
                              unsigned short* __restrict__ Blo1) {
  size_t idx = (size_t)blockIdx.x * blockDim.x + threadIdx.x;
  const size_t total = (size_t)2 * G4 * KCAT;
  if (idx >= total) return;
  int cc = (int)(idx % KCAT);
  size_t rowidx = idx / KCAT;          // d*G4 + p
  int p  = (int)(rowidx % G4);
  int dd = (int)(rowidx / G4);
  int j  = p >> 2;
  int ty = p & 3;
  size_t rbase = (size_t)dd * G4 + (size_t)(ty * H_SZ + j);

  float w0;
  if (cc < MAXLEN)      w0 = w_ih0[rbase * MAXLEN + cc];
  else if (cc < KIH)    w0 = 0.f;                             // zero pad 1000..1023
  else                  w0 = w_hh0[rbase * H_SZ + (cc - KIH)];
  unsigned short h0 = f2bf(w0);
  Bhi0[idx] = h0;
  Blo0[idx] = f2bf(w0 - bf2f(h0));

  float w1;
  if (cc < KIH)         w1 = w_ih1[rbase * KIH + cc];
  else                  w1 = w_hh1[rbase * H_SZ + (cc - KIH)];
  unsigned short h1 = f2bf(w1);
  Bhi1[idx] = h1;
  Blo1[idx] = f2bf(w1 - bf2f(h1));
}

__global__ void prep_b_kernel(const float* __restrict__ b_ih0,
                              const float* __restrict__ b_hh0,
                              const float* __restrict__ b_ih1,
                              const float* __restrict__ b_hh1,
                              float* __restrict__ bias0,
                              float* __restrict__ bias1) {
  int idx = blockIdx.x * blockDim.x + threadIdx.x;   // 0 .. 2*G4-1
  if (idx >= 2 * G4) return;
  int p  = idx % G4;
  int dd = idx / G4;
  int src = dd * G4 + (p & 3) * H_SZ + (p >> 2);
  bias0[idx] = b_ih0[src] + b_hh0[src];
  bias1[idx] = b_ih1[src] + b_hh1[src];
}

// ============================================================
// prep: one-hot bitmasks. bits[t][b][w] (uint32, w<32) has bit j set iff
// x[b, 32w+j] == t (and 32w+j < MAXLEN). 21*2048*128B = 5.5 MB total.
// ============================================================
__global__ void prep_x_kernel(const int* __restrict__ x,
                              unsigned int* __restrict__ bits) {
  int idx = blockIdx.x * blockDim.x + threadIdx.x;   // (b, w)
  if (idx >= B_SZ * 32) return;
  int b = idx >> 5;
  int w = idx & 31;
  const int* xr = x + (size_t)b * MAXLEN + w * 32;
  int xv[32];
#pragma unroll
  for (int j = 0; j < 32; ++j) {
    int k = w * 32 + j;
    xv[j] = (k < MAXLEN) ? xr[j] : -1;
  }
#pragma unroll
  for (int t = 0; t < TSTEPS; ++t) {
    unsigned int m = 0;
#pragma unroll
    for (int j = 0; j < 32; ++j)
      m |= (xv[j] == t) ? (1u << j) : 0u;
    bits[((size_t)t * B_SZ + b) * 32 + w] = m;
  }
}

// ============================================================
// one recurrent step. 1D grid of 512 blocks, XCD-swizzled decode.
// 512 threads = 8 waves (4 wr x 2 wc); wave: 2 M-tiles x 4 N-tiles.
// Double-buffered LDS, ONE barrier per K-iter; register prefetch depth 2.
// gates = [A_in | h] @ (Bhi [+ Blo for k>=KIH])^T + bias ; LSTM cell fused.
// ============================================================
template <int LAYER>
__global__ __launch_bounds__(512, 4)
void step_kernel(const unsigned int* __restrict__ xbits,     // [21,B,32] one-hot bits
                 const unsigned short* __restrict__ seq_in,   // [T,B,2H] bf16
                 const unsigned short* __restrict__ Bhi,      // [2,G4,KCAT] bf16
                 const unsigned short* __restrict__ Blo,      // [2,G4,KCAT] bf16
                 const float* __restrict__ bias,              // [2,G4] f32
                 const unsigned short* __restrict__ h_in,     // [2,B,H] bf16
                 unsigned short* __restrict__ h_out,          // [2,B,H] bf16
                 float* __restrict__ c_st,                    // [2,B,H] f32
                 unsigned short* __restrict__ seq_out,        // [T,B,2H]   (LAYER 0)
                 float* __restrict__ zacc,                    // [B,2H] f32 (LAYER 1)
                 const float* __restrict__ emb_w,             // [21] f32   (LAYER 1)
                 int step) {
  __shared__ union {
    struct {
      unsigned short A[BM * LDSK];    // 10 KB
      unsigned short Bh[BN * LDSK];   // 10 KB
      unsigned short Bl[BN * LDSK];   // 10 KB
    } t[2];                           // 60 KB double buffer
    float gc[BM * GPAD];              // 16.9 KB gates chunk (128 x 32 + pad)
  } sm;                               // union: 60 KB -> 2 blocks/CU

  const int tid  = threadIdx.x;
  const int lane = tid & 63;
  const int wave = tid >> 6;          // 0..7
  const int wr   = wave >> 1;         // 0..3  (M: wr*32 + mt*16)
  const int wc   = wave & 1;          // 0..1  (N: wc*64 + nt*16)
  const int q    = lane >> 4;
  const int r16  = lane & 15;

  // ---- XCD-swizzled block decode: bid = slot<<3 | xcd ----
  const int bid  = blockIdx.x;        // 0..511
  const int xcd  = bid & 7;
  const int slot = bid >> 3;          // 0..63 = d*32 + mb*2 + nsub
  const int nb   = xcd * 2 + (slot & 1);    // 0..15 n-block (pinned per XCD)
  const int mb   = (slot >> 1) & 15;        // 0..15 m-block
  const int d    = slot >> 5;               // direction

  const int tcur = d ? (TSTEPS - 1 - step) : step;
  const int n0   = nb * BN;           // permuted gate cols
  const int m0   = mb * BM;           // batch rows

  const unsigned short* Bh_mat = Bhi + (size_t)d * G4 * KCAT;
  const unsigned short* Bl_mat = Blo + (size_t)d * G4 * KCAT;
  const unsigned char*  xrow   = (const unsigned char*)xbits + ((size_t)tcur * B_SZ) * XROW;

  float bval[4];
#pragma unroll
  for (int nt = 0; nt < 4; ++nt)
    bval[nt] = bias[d * G4 + n0 + wc * 64 + nt * 16 + r16];

  f32x4 acc[2][4];
#pragma unroll
  for (int mt = 0; mt < 2; ++mt)
#pragma unroll
    for (int nt = 0; nt < 4; ++nt) {
      f32x4 z = {0.f, 0.f, 0.f, 0.f};
      acc[mt][nt] = z;
    }

  // staging: 512 chunks of 8 elts per [128 x 32] tile; 1 chunk/thread
  const int rstg = tid >> 2;            // tile row 0..127
  const int ostg = (tid & 3) * 8;       // k offset 0/8/16/24

  // ---- prefetch payload register sets (depth 2) ----
  ushort8 pbh[2], pbl[2], pva[2];
  unsigned int pbv[2];

  auto load_iter = [&](int kt, int s) {
    const int k0 = kt * BK;
    pbh[s] = *(const ushort8*)(Bh_mat + (size_t)(n0 + rstg) * KCAT + k0 + ostg);
    if (k0 >= KIH) {
      pbl[s] = *(const ushort8*)(Bl_mat + (size_t)(n0 + rstg) * KCAT + k0 + ostg);
      const unsigned short* Asrc = h_in + (size_t)d * B_SZ * H_SZ;
      pva[s] = *(const ushort8*)(Asrc + (size_t)(m0 + rstg) * H_SZ + (k0 - KIH) + ostg);
    } else if (LAYER == 0) {
      pbv[s] = xrow[(size_t)(m0 + rstg) * XROW + (k0 + ostg) / 8];   // 8 one-hot bits
    } else {
      const unsigned short* Asrc = seq_in + (size_t)tcur * B_SZ * (2 * H_SZ);
      pva[s] = *(const ushort8*)(Asrc + (size_t)(m0 + rstg) * (2 * H_SZ) + k0 + ostg);
    }
  };

  auto body = [&](int kt, int s) {     // s = kt & 1 (compile-time at call sites)
    const int k0 = kt * BK;
    const bool useLo = (k0 >= KIH);
    const bool onehot = (LAYER == 0) && (k0 < KIH);

    // ---- store payload (loaded 2 iters ago) into buffer s ----
    if (onehot) {
      unsigned int bv = pbv[s];
      unsigned int pk[4];
#pragma unroll
      for (int e = 0; e < 4; ++e) {
        unsigned int lo = (bv >> (2 * e))     & 1u;
        unsigned int hi = (bv >> (2 * e + 1)) & 1u;
        pk[e] = (lo ? 0x3F80u : 0u) | (hi ? 0x3F800000u : 0u);   // 2 packed bf16
      }
      *(uint4*)(sm.t[s].A + rstg * LDSK + ostg) = make_uint4(pk[0], pk[1], pk[2], pk[3]);
    } else {
      *(ushort8*)(sm.t[s].A + rstg * LDSK + ostg) = pva[s];
    }
    *(ushort8*)(sm.t[s].Bh + rstg * LDSK + ostg) = pbh[s];
    if (useLo)
      *(ushort8*)(sm.t[s].Bl + rstg * LDSK + ostg) = pbl[s];
    __syncthreads();   // the ONLY barrier this iteration (dbuf makes it safe)

    // ---- issue loads for iter kt+2 into the set just freed ----
    if (kt + 2 < NIT) load_iter(kt + 2, s);

    // ---- MFMA: 2x4 16x16 tiles per wave; +lo product on recurrent k ----
    // A/B fragment: m/n = lane&15, k = (lane>>4)*8 + j   [m89/m91 verified]
    bf16x8 af[2], bh[4];
#pragma unroll
    for (int mt = 0; mt < 2; ++mt)
      af[mt] = *(const bf16x8*)(sm.t[s].A + (wr * 32 + mt * 16 + r16) * LDSK + q * 8);
#pragma unroll
    for (int nt = 0; nt < 4; ++nt)
      bh[nt] = *(const bf16x8*)(sm.t[s].Bh + (wc * 64 + nt * 16 + r16) * LDSK + q * 8);
#pragma unroll
    for (int mt = 0; mt < 2; ++mt)
#pragma unroll
      for (int nt = 0; nt < 4; ++nt)
        acc[mt][nt] = __builtin_amdgcn_mfma_f32_16x16x32_bf16(af[mt], bh[nt], acc[mt][nt], 0, 0, 0);
    if (useLo) {
      bf16x8 bl[4];
#pragma unroll
      for (int nt = 0; nt < 4; ++nt)
        bl[nt] = *(const bf16x8*)(sm.t[s].Bl + (wc * 64 + nt * 16 + r16) * LDSK + q * 8);
#pragma unroll
      for (int mt = 0; mt < 2; ++mt)
#pragma unroll
        for (int nt = 0; nt < 4; ++nt)
          acc[mt][nt] = __builtin_amdgcn_mfma_f32_16x16x32_bf16(af[mt], bl[nt], acc[mt][nt], 0, 0, 0);
    }
  };

  load_iter(0, 0);
  load_iter(1, 1);
  for (int kt = 0; kt < NIT; kt += 2) {   // NIT=48 even; buffer index compile-time
    body(kt, 0);
    body(kt + 1, 1);
  }
  __syncthreads();   // all MFMA LDS reads done before gates scratch overwrite

  // ---- epilogue: 4 chunks of 32 gate-cols through 128x33 LDS scratch ----
  // C/D layout: col = lane&15, row = (lane>>4)*4 + reg   [m89/m91 verified]
  const int jbase = nb * 32;   // 32 hidden units per N-block
  const float ew = (LAYER == 1) ? emb_w[tcur] : 0.f;

#pragma unroll
  for (int cc2 = 0; cc2 < 4; ++cc2) {
    if (wc == (cc2 >> 1)) {
      const int ntb = (cc2 & 1) * 2;
#pragma unroll
      for (int nti = 0; nti < 2; ++nti) {
        const int nt = ntb + nti;
#pragma unroll
        for (int mt = 0; mt < 2; ++mt)
#pragma unroll
          for (int r = 0; r < 4; ++r) {
            int ml = wr * 32 + mt * 16 + q * 4 + r;
            int nl = nti * 16 + r16;
            sm.gc[ml * GPAD + nl] = acc[mt][nt][r] + bval[nt];
          }
      }
    }
    __syncthreads();

    // read: 1024 cells (128 rows x 8 col-quads), 2 per thread
#pragma unroll
    for (int it = 0; it < 2; ++it) {
      int cell = it * 512 + tid;
      int rl = cell >> 3;        // row 0..127
      int jq = cell & 7;         // col-quad within chunk
      const float4 g = *(const float4*)(&sm.gc[rl * GPAD + jq * 4]);
      float si = sigmoidf_(g.x);
      float sf = sigmoidf_(g.y);
      float tg = tanhf_(g.z);
      float so = sigmoidf_(g.w);
      int b = m0 + rl;
      int j = jbase + cc2 * 8 + jq;
      size_t cidx = ((size_t)d * B_SZ + b) * H_SZ + j;
      float cn = sf * c_st[cidx] + si * tg;
      float hv = so * tanhf_(cn);
      c_st[cidx] = cn;
      h_out[cidx] = f2bf(hv);
      if (LAYER == 0) {
        seq_out[((size_t)tcur * B_SZ + b) * (2 * H_SZ) + d * H_SZ + j] = f2bf(hv);
      } else {
        zacc[(size_t)b * (2 * H_SZ) + d * H_SZ + j] += ew * hv;
      }
    }
    __syncthreads();
  }
}

// ============================================================
// final: z[b,:] = zacc[b,:] + emb_b ; out = z @ fc_w^T + fc_b   (all f32)
// ============================================================
__global__ __launch_bounds__(256)
void final_kernel(const float* __restrict__ zacc,    // [B, 2H] f32
                  const float* __restrict__ emb_b,   // [1]
                  const float* __restrict__ fc_w,    // [10, 2H]
                  const float* __restrict__ fc_b,    // [10]
                  float* __restrict__ out) {         // [B, 10] f32
  const int b = blockIdx.x;
  const int tid = threadIdx.x;
  const int c0 = tid * 4;

  const float zb = emb_b[0];
  const float4 z4 = *(const float4*)(zacc + (size_t)b * (2 * H_SZ) + c0);
  float z0 = z4.x + zb, z1 = z4.y + zb, z2 = z4.z + zb, z3 = z4.w + zb;

  float part[NCLS];
#pragma unroll
  for (int nc = 0; nc < NCLS; ++nc) {
    const float4 f = *(const float4*)(fc_w + (size_t)nc * (2 * H_SZ) + c0);
    part[nc] = z0 * f.x + z1 * f.y + z2 * f.z + z3 * f.w;
  }
#pragma unroll
  for (int nc = 0; nc < NCLS; ++nc)
#pragma unroll
    for (int off2 = 32; off2 > 0; off2 >>= 1)
      part[nc] += __shfl_down(part[nc], off2);

  __shared__ float red[4][NCLS];
  if ((tid & 63) == 0) {
#pragma unroll
    for (int nc = 0; nc < NCLS; ++nc) red[tid >> 6][nc] = part[nc];
  }
  __syncthreads();
  if (tid < NCLS) {
    float s = red[0][tid] + red[1][tid] + red[2][tid] + red[3][tid] + fc_b[tid];
    out[b * NCLS + tid] = s;
  }
}

// ============================================================
extern "C" void kernel_launch(void* const* d_in, const int* in_sizes, int n_in,
                              void* d_out, int out_size, void* d_ws, size_t ws_size,
                              hipStream_t stream) {
  (void)in_sizes; (void)n_in; (void)out_size; (void)ws_size;

  const int*   x     = (const int*)d_in[0];
  const float* w_ih0 = (const float*)d_in[1];
  const float* w_hh0 = (const float*)d_in[2];
  const float* b_ih0 = (const float*)d_in[3];
  const float* b_hh0 = (const float*)d_in[4];
  const float* w_ih1 = (const float*)d_in[5];
  const float* w_hh1 = (const float*)d_in[6];
  const float* b_ih1 = (const float*)d_in[7];
  const float* b_hh1 = (const float*)d_in[8];
  const float* emb_w = (const float*)d_in[9];
  const float* emb_b = (const float*)d_in[10];
  const float* fc_w  = (const float*)d_in[11];
  const float* fc_b  = (const float*)d_in[12];

  // -------- workspace layout (~171 MB) --------
  char* ws = (char*)d_ws;
  size_t off = 0;
  auto alloc = [&](size_t bytes) -> void* {
    void* p = ws + off;
    off += (bytes + 255) & ~(size_t)255;
    return p;
  };
  const size_t bmat_b = (size_t)2 * G4 * KCAT * 2;              // 12.6 MB each
  const size_t h_b    = (size_t)2 * B_SZ * H_SZ * 2;            // 4.2 MB
  const size_t c_b    = (size_t)2 * B_SZ * H_SZ * 4;            // 8.4 MB
  const size_t seq_b  = (size_t)TSTEPS * B_SZ * (2 * H_SZ) * 2; // 88 MB
  const size_t z_b    = (size_t)B_SZ * (2 * H_SZ) * 4;          // 8.4 MB
  const size_t xb_b   = (size_t)TSTEPS * B_SZ * 32 * 4;         // 5.5 MB

  unsigned short* Bhi0 = (unsigned short*)alloc(bmat_b);
  unsigned short* Blo0 = (unsigned short*)alloc(bmat_b);
  unsigned short* Bhi1 = (unsigned short*)alloc(bmat_b);
  unsigned short* Blo1 = (unsigned short*)alloc(bmat_b);
  float*          bias0 = (float*)alloc((size_t)2 * G4 * 4);
  float*          bias1 = (float*)alloc((size_t)2 * G4 * 4);
  unsigned short* hA    = (unsigned short*)alloc(h_b);
  unsigned short* hB    = (unsigned short*)alloc(h_b);
  float*          cst   = (float*)alloc(c_b);
  float*          zacc  = (float*)alloc(z_b);
  unsigned int*   xbits = (unsigned int*)alloc(xb_b);
  unsigned short* seq0  = (unsigned short*)alloc(seq_b);

  // -------- prep --------
  {
    size_t total = (size_t)2 * G4 * KCAT;
    int blocks = (int)((total + 255) / 256);
    prep_w_kernel<<<blocks, 256, 0, stream>>>(w_ih0, w_hh0, w_ih1, w_hh1,
                                              Bhi0, Blo0, Bhi1, Blo1);
    prep_b_kernel<<<16, 256, 0, stream>>>(b_ih0, b_hh0, b_ih1, b_hh1, bias0, bias1);
    prep_x_kernel<<<(B_SZ * 32 + 255) / 256, 256, 0, stream>>>(x, xbits);
  }

  const int nblocks = 512;   // 1D, XCD-swizzled decode inside kernel

  // -------- layer 0 --------
  hipMemsetAsync(hA, 0, h_b, stream);
  hipMemsetAsync(cst, 0, c_b, stream);
  for (int s = 0; s < TSTEPS; ++s) {
    const unsigned short* hin  = (s & 1) ? hB : hA;
    unsigned short*       hout = (s & 1) ? hA : hB;
    step_kernel<0><<<nblocks, 512, 0, stream>>>(xbits, nullptr, Bhi0, Blo0, bias0, hin, hout, cst,
                                                seq0, nullptr, nullptr, s);
  }

  // -------- layer 1 (emb contraction fused into epilogue) --------
  hipMemsetAsync(hA, 0, h_b, stream);
  hipMemsetAsync(cst, 0, c_b, stream);
  hipMemsetAsync(zacc, 0, z_b, stream);
  for (int s = 0; s < TSTEPS; ++s) {
    const unsigned short* hin  = (s & 1) ? hB : hA;
    unsigned short*       hout = (s & 1) ? hA : hB;
    step_kernel<1><<<nblocks, 512, 0, stream>>>(nullptr, seq0, Bhi1, Blo1, bias1, hin, hout, cst,
                                                nullptr, zacc, emb_w, s);
  }

  // -------- fc --------
  final_kernel<<<B_SZ, 256, 0, stream>>>(zacc, emb_b, fc_w, fc_b, (float*)d_out);
}